// Round 5
// baseline (296.188 us; speedup 1.0000x reference)
//
#include <hip/hip_runtime.h>

#define EMB 2048
#define UDIM 256
#define KTOT 2304
#define NE 64
#define TOPK 8
#define SSH 6144              // shorts per k-step in wb (12288 B)
#define STEPB 12288           // bytes per k-step
#define KSPL 8                // K-split factor
#define SPS 9                 // k-steps per slice (72/8)
#define SLICEB (SPS * STEPB)  // 110592 B LDS slice
#define NTOK 16384
#define PART_OFF (1 << 20)    // partial buffer offset in workspace (bytes)

typedef __attribute__((ext_vector_type(8))) short short8;
typedef __attribute__((ext_vector_type(4))) float f32x4;
typedef __attribute__((ext_vector_type(4))) unsigned int u32x4;

__device__ __forceinline__ unsigned short bf16h(float x) {
  unsigned uu = __builtin_bit_cast(unsigned, x);
  return (unsigned short)((uu + 0x7FFFu + ((uu >> 16) & 1u)) >> 16);
}
__device__ __forceinline__ float bf2f(unsigned short s) {
  return __builtin_bit_cast(float, ((unsigned)s) << 16);
}

// packed RNE f32x2 -> bf16x2
__device__ __forceinline__ unsigned cvtpk(float a, float b) {
  unsigned r;
  asm("v_cvt_pk_bf16_f32 %0, %1, %2" : "=v"(r) : "v"(a), "v"(b));
  return r;
}

// ---- prep: W fp32 [2304][64] -> triple-split bf16 in MFMA-FRAGMENT order ----
// wb[kstep][plane][nt][lane][j]:  lane = (kk>>3)*16 + (n&15), j = kk&7
__global__ __launch_bounds__(256)
void prep_w(const float* __restrict__ W, unsigned short* __restrict__ wb) {
  const int flat = blockIdx.x * 256 + threadIdx.x;  // 0..147455
  const int k = flat >> 6;
  const int n = flat & 63;
  const float w = W[flat];
  const unsigned short h0 = bf16h(w);
  const float r1 = w - bf2f(h0);   // exact in fp32
  const unsigned short h1 = bf16h(r1);
  const float r2 = r1 - bf2f(h1);  // exact in fp32
  const unsigned short h2 = bf16h(r2);

  const int s = k >> 5;
  const int kk = k & 31;
  const int lane = (kk >> 3) * 16 + (n & 15);
  const int j = kk & 7;
  const int nt = n >> 4;
  const size_t base = (size_t)s * SSH + ((size_t)nt * 64 + lane) * 8 + j;
  wb[base] = h0;
  wb[base + 2048] = h1;
  wb[base + 4096] = h2;
}

// ---- split-K GEMM: B-stationary in LDS, barrier-free main loop ----
// Grid = 8 K-slices x 32 blocks. Block stages its 108 KB wb-slice to LDS
// ONCE; 8 waves then each compute 4 independent 16-token tiles over 288 k.
// B global traffic: 900 MB -> 28 MB (kills the ~8 TB/s L2/L3 roofline that
// pinned R0/R2/R4 at ~115 us). A is read exactly once (150 MB HBM floor).
__global__ __launch_bounds__(512, 2)
void gate_split(const float* __restrict__ h, const float* __restrict__ u,
                const unsigned short* __restrict__ wb,
                float* __restrict__ partial) {
  __shared__ __align__(1024) char lds[SLICEB];  // 108 KB -> 1 block/CU

  const int tid = threadIdx.x;
  const int lane = tid & 63;
  const int wid = __builtin_amdgcn_readfirstlane(tid >> 6);  // 0..7
  const int kq = blockIdx.x >> 5;   // K slice 0..7
  const int bb = blockIdx.x & 31;   // tile-group
  const int mm = lane & 15;         // A: token-in-tile | B: expert%16
  const int q8 = (lane >> 4) * 8;   // k-subgroup within frag

  // ---- stage wb slice (identity byte-map; LDS dest wave-uniform) ----
  const char* src = (const char*)wb + (size_t)kq * SLICEB + (size_t)lane * 16;
  for (int j = wid; j < SPS * 12; j += 8)  // 108 chunks of 1024 B
    __builtin_amdgcn_global_load_lds(
        (const __attribute__((address_space(1))) unsigned int*)(src + (size_t)j * 1024),
        (__attribute__((address_space(3))) unsigned int*)(lds + (size_t)j * 1024),
        16, 0, 0);
  __syncthreads();  // one-time drain; main loop below has no barriers

  const bool tail = (kq == KSPL - 1);
  const char* lb = lds + (size_t)lane * 16;

#pragma unroll 1
  for (int tt = 0; tt < 4; ++tt) {
    const int tile = (bb * 8 + wid) * 4 + tt;
    const int token = tile * 16 + mm;
    const float* hb = h + (size_t)token * EMB + kq * (SPS * 32) + q8;
    const float* ht = h + (size_t)token * EMB + 2016 + q8;
    const float* ub = u + (size_t)token * UDIM + q8;

    // burst-load the task's entire A slice: 18 dwordx4, max MLP,
    // static indices (nothing for the register allocator to sink/rotate)
    f32x4 A[2 * SPS];
#pragma unroll
    for (int s = 0; s < SPS; ++s) {
      const float* bs = !tail ? (hb + s * 32)
                              : (s == 0 ? ht : (ub + (s - 1) * 32));
      A[2 * s] = *(const f32x4*)bs;
      A[2 * s + 1] = *(const f32x4*)(bs + 4);
    }

    f32x4 acc[4];
#pragma unroll
    for (int nt = 0; nt < 4; ++nt) acc[nt] = 0.f;

#pragma unroll
    for (int s = 0; s < SPS; ++s) {
      short8 Bv[12];
#pragma unroll
      for (int q = 0; q < 12; ++q)
        Bv[q] = *(const short8*)(lb + (size_t)s * STEPB + q * 1024);

      const f32x4 c0 = A[2 * s], c1 = A[2 * s + 1];
      const float xs[8] = {c0[0], c0[1], c0[2], c0[3],
                           c1[0], c1[1], c1[2], c1[3]};
      u32x4 W0, W1, W2;
#pragma unroll
      for (int k2 = 0; k2 < 4; ++k2) {
        const float a = xs[2 * k2], bbv = xs[2 * k2 + 1];
        const unsigned p0 = cvtpk(a, bbv);
        const float a1 = a - __builtin_bit_cast(float, p0 << 16);
        const float b1 = bbv - __builtin_bit_cast(float, p0 & 0xFFFF0000u);
        const unsigned p1 = cvtpk(a1, b1);
        const float a2 = a1 - __builtin_bit_cast(float, p1 << 16);
        const float b2 = b1 - __builtin_bit_cast(float, p1 & 0xFFFF0000u);
        const unsigned p2 = cvtpk(a2, b2);
        W0[k2] = p0; W1[k2] = p1; W2[k2] = p2;
      }
      const short8 A0 = __builtin_bit_cast(short8, W0);
      const short8 A1 = __builtin_bit_cast(short8, W1);
      const short8 A2 = __builtin_bit_cast(short8, W2);

#pragma unroll
      for (int nt = 0; nt < 4; ++nt) {
        acc[nt] = __builtin_amdgcn_mfma_f32_16x16x32_bf16(A0, Bv[0 + nt], acc[nt], 0, 0, 0);
        acc[nt] = __builtin_amdgcn_mfma_f32_16x16x32_bf16(A0, Bv[4 + nt], acc[nt], 0, 0, 0);
        acc[nt] = __builtin_amdgcn_mfma_f32_16x16x32_bf16(A1, Bv[0 + nt], acc[nt], 0, 0, 0);
        acc[nt] = __builtin_amdgcn_mfma_f32_16x16x32_bf16(A1, Bv[4 + nt], acc[nt], 0, 0, 0);
        acc[nt] = __builtin_amdgcn_mfma_f32_16x16x32_bf16(A0, Bv[8 + nt], acc[nt], 0, 0, 0);
        acc[nt] = __builtin_amdgcn_mfma_f32_16x16x32_bf16(A2, Bv[0 + nt], acc[nt], 0, 0, 0);
      }
    }

    // ---- write partial tile: D row(token)=(lane>>4)*4+r, col=nt*16+mm ----
    const int rowb = (lane >> 4) * 4;
#pragma unroll
    for (int nt = 0; nt < 4; ++nt)
#pragma unroll
      for (int r = 0; r < 4; ++r)
        partial[((size_t)kq * NTOK + tile * 16 + rowb + r) * NE + nt * 16 + mm] =
            acc[nt][r];
  }
}

// ---- finalize: reduce 8 partials + bias + softmax + top-8 ----
__global__ __launch_bounds__(256)
void finalize(const float* __restrict__ partial, const float* __restrict__ b,
              float* __restrict__ out) {
  const int tid = threadIdx.x;
  const int lane = tid & 63;
  const int wid = tid >> 6;  // 0..3
  const int tok0 = blockIdx.x * 64;
  const float bias = b[lane];

#pragma unroll 1
  for (int tt = 0; tt < 16; ++tt) {
    const int t = tok0 + wid * 16 + tt;
    float g = bias;
#pragma unroll
    for (int s = 0; s < KSPL; ++s)
      g += partial[((size_t)s * NTOK + t) * NE + lane];

    float m = g;
#pragma unroll
    for (int off = 32; off > 0; off >>= 1)
      m = fmaxf(m, __shfl_xor(m, off));
    float pexp = __expf(g - m);
    float sum = pexp;
#pragma unroll
    for (int off = 32; off > 0; off >>= 1)
      sum += __shfl_xor(sum, off);
    const float pn = pexp / sum;

    float vv = pn;
    float topsum = 0.f;
    int sel = 0;
    for (int r = 0; r < TOPK; ++r) {
      float mv = vv;
      int mi = lane;
#pragma unroll
      for (int off = 32; off > 0; off >>= 1) {
        const float ov = __shfl_xor(mv, off);
        const int oi = __shfl_xor(mi, off);
        if (ov > mv || (ov == mv && oi < mi)) { mv = ov; mi = oi; }
      }
      topsum += mv;
      if (lane == mi) { sel = 1; vv = -1.f; }
    }

    out[(size_t)t * NE + lane] = sel ? pn / (topsum + 1e-9f) : 0.f;
  }
}

extern "C" void kernel_launch(void* const* d_in, const int* in_sizes, int n_in,
                              void* d_out, int out_size, void* d_ws, size_t ws_size,
                              hipStream_t stream) {
  const float* h = (const float*)d_in[0];
  const float* u = (const float*)d_in[1];
  const float* W = (const float*)d_in[2];
  const float* b = (const float*)d_in[3];
  float* out = (float*)d_out;

  unsigned short* wb = (unsigned short*)d_ws;           // 884736 B
  float* partial = (float*)((char*)d_ws + PART_OFF);    // 8*16384*64*4 = 33.5 MB

  hipLaunchKernelGGL(prep_w, dim3(KTOT * NE / 256), dim3(256), 0, stream, W, wb);
  hipLaunchKernelGGL(gate_split, dim3(KSPL * 32), dim3(512), 0, stream,
                     h, u, wb, partial);
  hipLaunchKernelGGL(finalize, dim3(NTOK / 64), dim3(256), 0, stream,
                     partial, b, out);
}

// Round 6
// 243.051 us; speedup vs baseline: 1.2186x; 1.2186x over previous
//
#include <hip/hip_runtime.h>

#define EMB 2048
#define UDIM 256
#define KTOT 2304
#define NE 64
#define TOPK 8
#define SSH 6144              // shorts per k-step in wb (12288 B)
#define STEPB 12288           // bytes per k-step
#define KSPL 8                // K-split factor
#define SPS 9                 // k-steps per slice (72/8)
#define SLICEB (SPS * STEPB)  // 110592 B LDS slice
#define NTOK 16384
#define PART_OFF (1 << 20)    // partial buffer offset in workspace (bytes)

typedef __attribute__((ext_vector_type(8))) short short8;
typedef __attribute__((ext_vector_type(4))) float f32x4;
typedef __attribute__((ext_vector_type(4))) unsigned int u32x4;

__device__ __forceinline__ unsigned short bf16h(float x) {
  unsigned uu = __builtin_bit_cast(unsigned, x);
  return (unsigned short)((uu + 0x7FFFu + ((uu >> 16) & 1u)) >> 16);
}
__device__ __forceinline__ float bf2f(unsigned short s) {
  return __builtin_bit_cast(float, ((unsigned)s) << 16);
}

// packed RNE f32x2 -> bf16x2
__device__ __forceinline__ unsigned cvtpk(float a, float b) {
  unsigned r;
  asm("v_cvt_pk_bf16_f32 %0, %1, %2" : "=v"(r) : "v"(a), "v"(b));
  return r;
}

// ---- prep: W fp32 [2304][64] -> triple-split bf16 in MFMA-FRAGMENT order ----
// wb[kstep][plane][nt][lane][j]:  lane = (kk>>3)*16 + (n&15), j = kk&7
__global__ __launch_bounds__(256)
void prep_w(const float* __restrict__ W, unsigned short* __restrict__ wb) {
  const int flat = blockIdx.x * 256 + threadIdx.x;  // 0..147455
  const int k = flat >> 6;
  const int n = flat & 63;
  const float w = W[flat];
  const unsigned short h0 = bf16h(w);
  const float r1 = w - bf2f(h0);   // exact in fp32
  const unsigned short h1 = bf16h(r1);
  const float r2 = r1 - bf2f(h1);  // exact in fp32
  const unsigned short h2 = bf16h(r2);

  const int s = k >> 5;
  const int kk = k & 31;
  const int lane = (kk >> 3) * 16 + (n & 15);
  const int j = kk & 7;
  const int nt = n >> 4;
  const size_t base = (size_t)s * SSH + ((size_t)nt * 64 + lane) * 8 + j;
  wb[base] = h0;
  wb[base + 2048] = h1;
  wb[base + 4096] = h2;
}

// ---- split-K GEMM: B-stationary in LDS, barrier-free, A software-pipelined --
// Grid = 8 K-slices x 32 blocks. Block stages its 108 KB wb-slice to LDS
// ONCE; 8 waves each compute 4 independent 16-token tiles over 288 k.
// Cross-tile A-prefetch: next tile's 18-load burst issues mid-compute of the
// current tile (sched_barrier pins it against sinking, rule #18; two named
// A-buffers avoid runtime indexing, rule #20). Peak VGPR ~220 < 256 cap.
__global__ __launch_bounds__(512, 2)
void gate_split(const float* __restrict__ h, const float* __restrict__ u,
                const unsigned short* __restrict__ wb,
                float* __restrict__ partial) {
  __shared__ __align__(1024) char lds[SLICEB];  // 108 KB -> 1 block/CU

  const int tid = threadIdx.x;
  const int lane = tid & 63;
  const int wid = __builtin_amdgcn_readfirstlane(tid >> 6);  // 0..7
  const int kq = blockIdx.x >> 5;   // K slice 0..7
  const int bb = blockIdx.x & 31;   // tile-group
  const int mm = lane & 15;         // A: token-in-tile | B: expert%16
  const int q8 = (lane >> 4) * 8;   // k-subgroup within frag

  // ---- stage wb slice (identity byte-map; LDS dest wave-uniform) ----
  const char* src = (const char*)wb + (size_t)kq * SLICEB + (size_t)lane * 16;
  for (int j = wid; j < SPS * 12; j += 8)  // 108 chunks of 1024 B
    __builtin_amdgcn_global_load_lds(
        (const __attribute__((address_space(1))) unsigned int*)(src + (size_t)j * 1024),
        (__attribute__((address_space(3))) unsigned int*)(lds + (size_t)j * 1024),
        16, 0, 0);
  __syncthreads();  // one-time drain; main loop below has no barriers

  const bool tail = (kq == KSPL - 1);
  const char* lb = lds + (size_t)lane * 16;
  const int tb = (bb * 8 + wid) * 4;

  f32x4 acc[4];
#pragma unroll
  for (int nt = 0; nt < 4; ++nt) acc[nt] = 0.f;

  auto aload = [&](int tile, f32x4* A) {
    const int token = tile * 16 + mm;
    const float* hb = h + (size_t)token * EMB + kq * (SPS * 32) + q8;
    const float* ht = h + (size_t)token * EMB + 2016 + q8;
    const float* ub = u + (size_t)token * UDIM + q8;
#pragma unroll
    for (int s = 0; s < SPS; ++s) {
      const float* bs = !tail ? (hb + s * 32)
                              : (s == 0 ? ht : (ub + (s - 1) * 32));
      A[2 * s] = *(const f32x4*)bs;
      A[2 * s + 1] = *(const f32x4*)(bs + 4);
    }
  };

  auto stepf = [&](const f32x4* A, int s) {
    short8 Bv[12];
#pragma unroll
    for (int q = 0; q < 12; ++q)
      Bv[q] = *(const short8*)(lb + (size_t)s * STEPB + q * 1024);

    const f32x4 c0 = A[2 * s], c1 = A[2 * s + 1];
    const float xs[8] = {c0[0], c0[1], c0[2], c0[3],
                         c1[0], c1[1], c1[2], c1[3]};
    u32x4 W0, W1, W2;
#pragma unroll
    for (int k2 = 0; k2 < 4; ++k2) {
      const float a = xs[2 * k2], bbv = xs[2 * k2 + 1];
      const unsigned p0 = cvtpk(a, bbv);
      const float a1 = a - __builtin_bit_cast(float, p0 << 16);
      const float b1 = bbv - __builtin_bit_cast(float, p0 & 0xFFFF0000u);
      const unsigned p1 = cvtpk(a1, b1);
      const float a2 = a1 - __builtin_bit_cast(float, p1 << 16);
      const float b2 = b1 - __builtin_bit_cast(float, p1 & 0xFFFF0000u);
      const unsigned p2 = cvtpk(a2, b2);
      W0[k2] = p0; W1[k2] = p1; W2[k2] = p2;
    }
    const short8 A0 = __builtin_bit_cast(short8, W0);
    const short8 A1 = __builtin_bit_cast(short8, W1);
    const short8 A2 = __builtin_bit_cast(short8, W2);

#pragma unroll
    for (int nt = 0; nt < 4; ++nt) {
      acc[nt] = __builtin_amdgcn_mfma_f32_16x16x32_bf16(A0, Bv[0 + nt], acc[nt], 0, 0, 0);
      acc[nt] = __builtin_amdgcn_mfma_f32_16x16x32_bf16(A0, Bv[4 + nt], acc[nt], 0, 0, 0);
      acc[nt] = __builtin_amdgcn_mfma_f32_16x16x32_bf16(A1, Bv[0 + nt], acc[nt], 0, 0, 0);
      acc[nt] = __builtin_amdgcn_mfma_f32_16x16x32_bf16(A1, Bv[4 + nt], acc[nt], 0, 0, 0);
      acc[nt] = __builtin_amdgcn_mfma_f32_16x16x32_bf16(A0, Bv[8 + nt], acc[nt], 0, 0, 0);
      acc[nt] = __builtin_amdgcn_mfma_f32_16x16x32_bf16(A2, Bv[0 + nt], acc[nt], 0, 0, 0);
    }
  };

  auto steps = [&](const f32x4* A, int s0, int s1) {
#pragma unroll
    for (int s = s0; s < s1; ++s) stepf(A, s);
  };

  auto store = [&](int tile) {
    const int rowb = (lane >> 4) * 4;
#pragma unroll
    for (int nt = 0; nt < 4; ++nt) {
#pragma unroll
      for (int r = 0; r < 4; ++r)
        partial[((size_t)kq * NTOK + tile * 16 + rowb + r) * NE + nt * 16 + mm] =
            acc[nt][r];
      acc[nt] = 0.f;
    }
  };

  f32x4 Aa[2 * SPS], Ab[2 * SPS];
  // static pipeline: next-tile burst issues mid-compute, lands during H2+H1'
  aload(tb + 0, Aa);
  steps(Aa, 0, 4);
  aload(tb + 1, Ab);
  __builtin_amdgcn_sched_barrier(0);
  steps(Aa, 4, SPS);  store(tb + 0);
  steps(Ab, 0, 4);
  aload(tb + 2, Aa);
  __builtin_amdgcn_sched_barrier(0);
  steps(Ab, 4, SPS);  store(tb + 1);
  steps(Aa, 0, 4);
  aload(tb + 3, Ab);
  __builtin_amdgcn_sched_barrier(0);
  steps(Aa, 4, SPS);  store(tb + 2);
  steps(Ab, 0, SPS);  store(tb + 3);
}

// ---- finalize: reduce 8 partials + bias + softmax + top-8, 1 token/wave ----
__global__ __launch_bounds__(256)
void finalize(const float* __restrict__ partial, const float* __restrict__ b,
              float* __restrict__ out) {
  const int tid = threadIdx.x;
  const int lane = tid & 63;
  const int wv = tid >> 6;  // 0..3
  const int t = blockIdx.x * 4 + wv;  // token
  const float bias = b[lane];

  float g = bias;
#pragma unroll
  for (int s = 0; s < KSPL; ++s)
    g += partial[((size_t)s * NTOK + t) * NE + lane];

  float m = g;
#pragma unroll
  for (int off = 32; off > 0; off >>= 1)
    m = fmaxf(m, __shfl_xor(m, off));
  float pexp = __expf(g - m);
  float sum = pexp;
#pragma unroll
  for (int off = 32; off > 0; off >>= 1)
    sum += __shfl_xor(sum, off);
  const float pn = pexp / sum;

  float vv = pn;
  float topsum = 0.f;
  int sel = 0;
  for (int r = 0; r < TOPK; ++r) {
    float mv = vv;
    int mi = lane;
#pragma unroll
    for (int off = 32; off > 0; off >>= 1) {
      const float ov = __shfl_xor(mv, off);
      const int oi = __shfl_xor(mi, off);
      if (ov > mv || (ov == mv && oi < mi)) { mv = ov; mi = oi; }
    }
    topsum += mv;
    if (lane == mi) { sel = 1; vv = -1.f; }
  }

  out[(size_t)t * NE + lane] = sel ? pn / (topsum + 1e-9f) : 0.f;
}

extern "C" void kernel_launch(void* const* d_in, const int* in_sizes, int n_in,
                              void* d_out, int out_size, void* d_ws, size_t ws_size,
                              hipStream_t stream) {
  const float* h = (const float*)d_in[0];
  const float* u = (const float*)d_in[1];
  const float* W = (const float*)d_in[2];
  const float* b = (const float*)d_in[3];
  float* out = (float*)d_out;

  unsigned short* wb = (unsigned short*)d_ws;           // 884736 B
  float* partial = (float*)((char*)d_ws + PART_OFF);    // 8*16384*64*4 = 33.5 MB

  hipLaunchKernelGGL(prep_w, dim3(KTOT * NE / 256), dim3(256), 0, stream, W, wb);
  hipLaunchKernelGGL(gate_split, dim3(KSPL * 32), dim3(512), 0, stream,
                     h, u, wb, partial);
  hipLaunchKernelGGL(finalize, dim3(NTOK / 4), dim3(256), 0, stream,
                     partial, b, out);
}